// Round 4
// baseline (6634.190 us; speedup 1.0000x reference)
//
#include <hip/hip_runtime.h>
#include <hip/hip_bf16.h>

#define EPSV 1e-5f
constexpr int NB = 32;

__device__ inline float ldv(const float* p) { return *p; }
__device__ inline float ldv(const __hip_bfloat16* p) { return __bfloat162float(*p); }
__device__ inline void stv(float* p, float v) { *p = v; }
__device__ inline void stv(__hip_bfloat16* p, float v) { *p = __float2bfloat16(v); }

// ---------------- deterministic 2-stage per-channel reduction ----------------
template<typename T>
__global__ __launch_bounds__(256) void reduce_partial(
    const T* __restrict__ in, int spatial, int C, int nb,
    float* __restrict__ part, int totb, int boff)
{
  const int c = blockIdx.y;
  const int b = blockIdx.x;
  const int nblk = gridDim.x;
  float s = 0.f, s2 = 0.f;
  for (int n = 0; n < nb; ++n) {
    const T* p = in + (size_t)(n * C + c) * spatial;
    for (int i = b * 256 + threadIdx.x; i < spatial; i += nblk * 256) {
      float v = ldv(p + i);
      s += v; s2 += v * v;
    }
  }
  __shared__ float sh[256], sh2[256];
  int tid = threadIdx.x;
  sh[tid] = s; sh2[tid] = s2;
  __syncthreads();
  for (int off = 128; off > 0; off >>= 1) {
    if (tid < off) { sh[tid] += sh[tid + off]; sh2[tid] += sh2[tid + off]; }
    __syncthreads();
  }
  if (tid == 0) {
    part[((size_t)c * totb + boff + b) * 2 + 0] = sh[0];
    part[((size_t)c * totb + boff + b) * 2 + 1] = sh2[0];
  }
}

__global__ __launch_bounds__(64) void reduce_final(
    const float* __restrict__ part, int nblk, int C, float* __restrict__ sums)
{
  const int c = blockIdx.x;
  float s = 0.f, s2 = 0.f;
  for (int b = threadIdx.x; b < nblk; b += 64) {
    s  += part[((size_t)c * nblk + b) * 2 + 0];
    s2 += part[((size_t)c * nblk + b) * 2 + 1];
  }
  for (int off = 32; off > 0; off >>= 1) {
    s  += __shfl_down(s, off);
    s2 += __shfl_down(s2, off);
  }
  if (threadIdx.x == 0) { sums[c] = s; sums[C + c] = s2; }
}

// ---------------- fused (BN[+bias+ReLU] on load) conv3d, k=5 s=2 p=3 ----------------
template<typename Tin, typename Tout, int IN, int OUT, int CIN, int COUT, int OHT, bool RB>
__global__ __launch_bounds__(256) void conv_k(
    const Tin* __restrict__ in, const float* __restrict__ w,
    const float* __restrict__ bias, const float* __restrict__ stats,
    Tout* __restrict__ out, int n_in0, int n_out0)
{
  constexpr int R  = 2 * OUT + 3;     // patch cols
  constexpr int RR = 2 * OHT + 3;     // patch rows
  constexpr int SP = OHT * OUT;       // spatial outputs per tile
  constexpr int P  = (SP + 31) / 32;  // passes per thread
  constexpr int OHTILES = (OUT + OHT - 1) / OHT;
  constexpr int PATCH = 5 * RR * R;
  constexpr float CNTI = 1.0f / ((float)NB * IN * IN * IN);

  __shared__ float patch[PATCH];
  __shared__ float wsh[16 * 125];

  const int tid = threadIdx.x;
  const int co0 = blockIdx.x * 16;
  const int od  = blockIdx.y / OHTILES;
  const int oht = blockIdx.y % OHTILES;
  const int oh_base = oht * OHT;
  const int co_sub = tid & 7;
  const int sb = tid >> 3;

  int rowb[P], colb[P];
  #pragma unroll
  for (int p = 0; p < P; ++p) {
    int s = sb + 32 * p;
    int sc = (s < SP) ? s : 0;        // clamp; invalid passes never written
    int ohs = sc / OUT;
    int ow  = sc - ohs * OUT;
    rowb[p] = ohs * 2;
    colb[p] = ow * 2;
  }

  float acc0[P], acc1[P];
  #pragma unroll
  for (int p = 0; p < P; ++p) { acc0[p] = 0.f; acc1[p] = 0.f; }

  for (int cin = 0; cin < CIN; ++cin) {
    const float mean = stats[cin] * CNTI;
    const float var  = stats[CIN + cin] * CNTI - mean * mean;
    const float inv  = rsqrtf(var + EPSV);
    float bv = 0.f;
    if constexpr (RB) bv = bias[cin];

    __syncthreads();   // protect previous iteration's patch reads
    const Tin* inc = in + (size_t)((n_in0 + blockIdx.z) * CIN + cin) * (IN * IN * IN);
    for (int idx = tid; idx < PATCH; idx += 256) {
      int kd   = idx / (RR * R);
      int rem  = idx - kd * (RR * R);
      int r    = rem / R;
      int ccol = rem - r * R;
      int id = od * 2 - 3 + kd;
      int ih = oh_base * 2 + r - 3;
      int iw = ccol - 3;
      float v = 0.f;
      if ((unsigned)id < (unsigned)IN && (unsigned)ih < (unsigned)IN &&
          (unsigned)iw < (unsigned)IN) {
        float x = ldv(inc + (id * IN + ih) * IN + iw);
        x = (x - mean) * inv;
        if constexpr (RB) { x += bv; x = fmaxf(x, 0.f); }
        v = x;
      }
      patch[idx] = v;
    }
    for (int idx = tid; idx < 16 * 125; idx += 256) {
      int cs = idx / 125;
      int k  = idx - cs * 125;
      int co = co0 + cs;
      wsh[idx] = (co < COUT) ? w[(size_t)(co * CIN + cin) * 125 + k] : 0.f;
    }
    __syncthreads();

    #pragma unroll 1   // keep I$ footprint sane; inner 25*P unrolled
    for (int kd = 0; kd < 5; ++kd) {
      #pragma unroll
      for (int kh = 0; kh < 5; ++kh) {
        #pragma unroll
        for (int kw = 0; kw < 5; ++kw) {
          const int k = (kd * 5 + kh) * 5 + kw;
          const float wa = wsh[co_sub * 125 + k];
          const float wb = wsh[(co_sub + 8) * 125 + k];
          #pragma unroll
          for (int p = 0; p < P; ++p) {
            float pv = patch[(kd * RR + rowb[p] + kh) * R + colb[p] + kw];
            acc0[p] += pv * wa;
            acc1[p] += pv * wb;
          }
        }
      }
    }
  }

  const int co_a = co0 + co_sub;
  const int co_b = co_a + 8;
  const int no = n_out0 + blockIdx.z;
  #pragma unroll
  for (int p = 0; p < P; ++p) {
    int s = sb + 32 * p;
    if (s < SP) {
      int ohs = s / OUT;
      int ow  = s - ohs * OUT;
      int oh  = oh_base + ohs;
      if (oh < OUT) {
        if (co_a < COUT)
          stv(out + ((size_t)(no * COUT + co_a) * OUT + od) * (OUT * OUT) + oh * OUT + ow, acc0[p]);
        if (co_b < COUT)
          stv(out + ((size_t)(no * COUT + co_b) * OUT + od) * (OUT * OUT) + oh * OUT + ow, acc1[p]);
      }
    }
  }
}

// ---------------- global avg pool + affine batch-dim BN ----------------
__global__ __launch_bounds__(320) void pool_bn(
    const float* __restrict__ y3, const float* __restrict__ gamma,
    const float* __restrict__ beta, float* __restrict__ out)
{
  __shared__ float pool[320];
  const int t = threadIdx.x;      // 0..319
  const int n = t / 10, c = t % 10;
  const float* p = y3 + (n * 10 + c) * 216;
  float s = 0.f;
  for (int i = 0; i < 216; ++i) s += p[i];
  const float pv = s * (1.0f / 216.0f);
  pool[t] = pv;
  __syncthreads();
  float m = 0.f, m2 = 0.f;
  for (int nn = 0; nn < 32; ++nn) {
    float v = pool[nn * 10 + c];
    m += v; m2 += v * v;
  }
  m *= (1.0f / 32.0f);
  m2 = m2 * (1.0f / 32.0f) - m * m;
  out[t] = (pv - m) * rsqrtf(m2 + EPSV) * gamma[c] + beta[c];
}

// ---------------- launcher ----------------
using bf16 = __hip_bfloat16;

extern "C" void kernel_launch(void* const* d_in, const int* in_sizes, int n_in,
                              void* d_out, int out_size, void* d_ws, size_t ws_size,
                              hipStream_t stream)
{
  const float* x  = (const float*)d_in[0];
  const float* w0 = (const float*)d_in[1];
  const float* b0 = (const float*)d_in[2];
  const float* w1 = (const float*)d_in[3];
  const float* b1 = (const float*)d_in[4];
  const float* w2 = (const float*)d_in[5];
  const float* b2 = (const float*)d_in[6];
  const float* w3 = (const float*)d_in[7];
  const float* gamma = (const float*)d_in[8];
  const float* beta  = (const float*)d_in[9];
  float* out = (float*)d_out;

  // ---- workspace layout (bytes, 256B aligned), sized to fit small ws ----
  char* base = (char*)d_ws;
  size_t off = 0;
  auto alloc = [&](size_t bytes) -> void* {
    void* p = base + off;
    off = (off + bytes + 255) & ~(size_t)255;
    return p;
  };
  bf16*  y1    = (bf16*)alloc((size_t)9704448 * 2);   // [32,52,18^3]
  bf16*  y2    = (bf16*)alloc((size_t)1664000 * 2);   // [32,52,10^3]
  float* y3    = (float*)alloc((size_t)69120 * 4);    // [32,10,6^3]
  float* st_in = (float*)alloc(1024);
  float* st0   = (float*)alloc(1024);
  float* st1   = (float*)alloc(1024);
  float* st2   = (float*)alloc(1024);
  float* part  = (float*)alloc(65536);
  // y0 region: whatever remains
  bf16* y0 = (bf16*)(base + off);
  size_t rem = (ws_size > off) ? (ws_size - off) : 0;
  const size_t Y0_IMG = (size_t)52 * 35937;           // elems per image
  int CH;
  if (rem >= Y0_IMG * 32 * 2)      CH = 32;           // full batch resident
  else if (rem >= Y0_IMG * 16 * 2) CH = 16;
  else if (rem >= Y0_IMG * 8 * 2)  CH = 8;
  else if (rem >= Y0_IMG * 4 * 2)  CH = 4;
  else if (rem >= Y0_IMG * 2 * 2)  CH = 2;
  else                             CH = 1;            // ~27 MB total floor

  // input BN stats (over x)
  reduce_partial<float><<<dim3(128, 1), 256, 0, stream>>>(x, 64 * 64 * 64, 1, NB, part, 128, 0);
  reduce_final<<<1, 64, 0, stream>>>(part, 128, 1, st_in);

  if (CH == 32) {
    // conv0: 1 -> 52, 64 -> 33 (BN(x) on load)
    conv_k<float, bf16, 64, 33, 1, 52, 8, false>
        <<<dim3(4, 165, 32), 256, 0, stream>>>(x, w0, nullptr, st_in, y0, 0, 0);
    reduce_partial<bf16><<<dim3(32, 52), 256, 0, stream>>>(y0, 35937, 52, 32, part, 32, 0);
    reduce_final<<<52, 64, 0, stream>>>(part, 32, 52, st0);
    // conv1: 52 -> 52, 33 -> 18 (BN+b0+ReLU on load)
    conv_k<bf16, bf16, 33, 18, 52, 52, 18, true>
        <<<dim3(4, 18, 32), 256, 0, stream>>>(y0, w1, b0, st0, y1, 0, 0);
  } else {
    const int nch = 32 / CH;
    // pass 1: conv0 per chunk + stats partials (y0 buffer reused per chunk)
    for (int ck = 0; ck < nch; ++ck) {
      conv_k<float, bf16, 64, 33, 1, 52, 8, false>
          <<<dim3(4, 165, CH), 256, 0, stream>>>(x, w0, nullptr, st_in, y0, ck * CH, 0);
      reduce_partial<bf16><<<dim3(CH, 52), 256, 0, stream>>>(y0, 35937, 52, CH, part, 32, ck * CH);
    }
    reduce_final<<<52, 64, 0, stream>>>(part, 32, 52, st0);
    // pass 2: recompute conv0 (bit-identical) + conv1 per chunk
    for (int ck = 0; ck < nch; ++ck) {
      conv_k<float, bf16, 64, 33, 1, 52, 8, false>
          <<<dim3(4, 165, CH), 256, 0, stream>>>(x, w0, nullptr, st_in, y0, ck * CH, 0);
      conv_k<bf16, bf16, 33, 18, 52, 52, 18, true>
          <<<dim3(4, 18, CH), 256, 0, stream>>>(y0, w1, b0, st0, y1, 0, ck * CH);
    }
  }

  // stats of y1
  reduce_partial<bf16><<<dim3(4, 52), 256, 0, stream>>>(y1, 5832, 52, 32, part, 4, 0);
  reduce_final<<<52, 64, 0, stream>>>(part, 4, 52, st1);
  // conv2: 52 -> 52, 18 -> 10 (BN+b1+ReLU on load)
  conv_k<bf16, bf16, 18, 10, 52, 52, 10, true>
      <<<dim3(4, 10, 32), 256, 0, stream>>>(y1, w2, b1, st1, y2, 0, 0);
  reduce_partial<bf16><<<dim3(1, 52), 256, 0, stream>>>(y2, 1000, 52, 32, part, 1, 0);
  reduce_final<<<52, 64, 0, stream>>>(part, 1, 52, st2);
  // conv3: 52 -> 10, 10 -> 6 (BN+b2+ReLU on load)
  conv_k<bf16, float, 10, 6, 52, 10, 6, true>
      <<<dim3(1, 6, 32), 256, 0, stream>>>(y2, w3, b2, st2, y3, 0, 0);
  // pool + output batch-norm
  pool_bn<<<1, 320, 0, stream>>>(y3, gamma, beta, out);
}

// Round 5
// 2683.852 us; speedup vs baseline: 2.4719x; 2.4719x over previous
//
#include <hip/hip_runtime.h>
#include <hip/hip_bf16.h>

#define EPSV 1e-5f
constexpr int NB = 32;

typedef short bf16x8 __attribute__((ext_vector_type(8)));
typedef short short4v __attribute__((ext_vector_type(4)));
typedef float f32x4 __attribute__((ext_vector_type(4)));

__device__ inline float bf2f(short s) {
  return __uint_as_float(((unsigned)(unsigned short)s) << 16);
}
__device__ inline short f2bf(float f) {
  unsigned u = __float_as_uint(f);
  unsigned r = (u + 0x7FFFu + ((u >> 16) & 1u)) >> 16;
  return (short)r;
}

// ---------------- x stats (NCDHW, C=1) ----------------
__global__ __launch_bounds__(256) void reduce_partial_f32(
    const float* __restrict__ in, int spatial, float* __restrict__ part,
    int totb, int boff)
{
  const int b = blockIdx.x;
  const int nblk = gridDim.x;
  float s = 0.f, s2 = 0.f;
  for (int n = 0; n < NB; ++n) {
    const float* p = in + (size_t)n * spatial;
    for (int i = b * 256 + threadIdx.x; i < spatial; i += nblk * 256) {
      float v = p[i];
      s += v; s2 += v * v;
    }
  }
  __shared__ float sh[256], sh2[256];
  int tid = threadIdx.x;
  sh[tid] = s; sh2[tid] = s2;
  __syncthreads();
  for (int off = 128; off > 0; off >>= 1) {
    if (tid < off) { sh[tid] += sh[tid + off]; sh2[tid] += sh2[tid + off]; }
    __syncthreads();
  }
  if (tid == 0) {
    part[(size_t)(boff + b) * 2 + 0] = sh[0];
    part[(size_t)(boff + b) * 2 + 1] = sh2[0];
  }
}

// ---------------- channels-last per-channel stats ----------------
__global__ __launch_bounds__(256) void reduce_cl(
    const short* __restrict__ y, int rowlen, long nrows,
    float* __restrict__ part, int totb, int boff)
{
  const int b = blockIdx.x, nblk = gridDim.x;
  const int c = threadIdx.x & 63, seg = threadIdx.x >> 6;
  float s = 0.f, s2 = 0.f;
  if (c < rowlen) {
    for (long r = (long)b * 4 + seg; r < nrows; r += (long)nblk * 4) {
      float v = bf2f(y[r * rowlen + c]);
      s += v; s2 += v * v;
    }
  }
  __shared__ float sh[4][64], sh2[4][64];
  sh[seg][c] = s; sh2[seg][c] = s2;
  __syncthreads();
  if (seg == 0) {
    float a = sh[0][c] + sh[1][c] + sh[2][c] + sh[3][c];
    float a2 = sh2[0][c] + sh2[1][c] + sh2[2][c] + sh2[3][c];
    part[((size_t)c * totb + boff + b) * 2 + 0] = a;
    part[((size_t)c * totb + boff + b) * 2 + 1] = a2;
  }
}

__global__ __launch_bounds__(64) void reduce_final(
    const float* __restrict__ part, int nblk, int C, float* __restrict__ sums)
{
  const int c = blockIdx.x;
  float s = 0.f, s2 = 0.f;
  for (int b = threadIdx.x; b < nblk; b += 64) {
    s  += part[((size_t)c * nblk + b) * 2 + 0];
    s2 += part[((size_t)c * nblk + b) * 2 + 1];
  }
  for (int off = 32; off > 0; off >>= 1) {
    s  += __shfl_down(s, off);
    s2 += __shfl_down(s2, off);
  }
  if (threadIdx.x == 0) { sums[c] = s; sums[C + c] = s2; }
}

// ---------------- stats -> per-channel affine (a*x + c, for relu(BN(x)+b)) ----
__global__ __launch_bounds__(64) void aff_k(
    const float* __restrict__ st, const float* __restrict__ bias,
    float cnt_inv, int creal, float* __restrict__ a, float* __restrict__ c)
{
  int t = threadIdx.x;
  float mean = st[t] * cnt_inv;
  float var  = st[64 + t] * cnt_inv - mean * mean;
  float inv  = rsqrtf(var + EPSV);
  bool ok = t < creal;
  a[t] = ok ? inv : 0.f;
  c[t] = ok ? (-mean * inv + bias[t]) : 0.f;
}

// ---------------- weight repack: w[CO][CIN][125] fp32 -> wt[125][COP][64] bf16
__global__ __launch_bounds__(256) void repack_k(
    const float* __restrict__ w, short* __restrict__ wt,
    int CO, int CIN, int COP)
{
  long total = 125L * COP * 64;
  for (long idx = (long)blockIdx.x * 256 + threadIdx.x; idx < total;
       idx += (long)gridDim.x * 256) {
    int tap = (int)(idx / (COP * 64));
    int r   = (int)(idx % (COP * 64));
    int co = r >> 6, ci = r & 63;
    float v = (co < CO && ci < CIN) ? w[((size_t)co * CIN + ci) * 125 + tap] : 0.f;
    wt[idx] = f2bf(v);
  }
}

// ---------------- conv0: VALU, CIN=1, BN(x) on load, channels-last-52 store ---
__global__ __launch_bounds__(256) void conv0_k(
    const float* __restrict__ in, const float* __restrict__ w,
    const float* __restrict__ stats, short* __restrict__ out,
    int n_in0, int n_out0)
{
  constexpr int IN = 64, OUT = 33, OHT = 8;
  constexpr int R  = 2 * OUT + 3;
  constexpr int RR = 2 * OHT + 3;
  constexpr int SP = OHT * OUT;
  constexpr int P  = (SP + 31) / 32;      // 9
  constexpr int OHTILES = (OUT + OHT - 1) / OHT;   // 5 -> grid.y = 33*5=165
  constexpr int PATCH = 5 * RR * R;
  constexpr float CNTI = 1.0f / ((float)NB * IN * IN * IN);

  __shared__ float patch[PATCH];
  __shared__ float wsh[16 * 125];

  const int tid = threadIdx.x;
  const int co0 = blockIdx.x * 16;
  const int od  = blockIdx.y / OHTILES;
  const int oht = blockIdx.y % OHTILES;
  const int oh_base = oht * OHT;
  const int co_sub = tid & 7;
  const int sb = tid >> 3;

  int rowb[P], colb[P];
  #pragma unroll
  for (int p = 0; p < P; ++p) {
    int s = sb + 32 * p;
    int sc = (s < SP) ? s : 0;
    int ohs = sc / OUT;
    int ow  = sc - ohs * OUT;
    rowb[p] = ohs * 2;
    colb[p] = ow * 2;
  }
  float acc0[P], acc1[P];
  #pragma unroll
  for (int p = 0; p < P; ++p) { acc0[p] = 0.f; acc1[p] = 0.f; }

  const float mean = stats[0] * CNTI;
  const float var  = stats[1] * CNTI - mean * mean;
  const float inv  = rsqrtf(var + EPSV);

  const float* inc = in + (size_t)(n_in0 + blockIdx.z) * (IN * IN * IN);
  for (int idx = tid; idx < PATCH; idx += 256) {
    int kd   = idx / (RR * R);
    int rem  = idx - kd * (RR * R);
    int r    = rem / R;
    int ccol = rem - r * R;
    int id = od * 2 - 3 + kd;
    int ih = oh_base * 2 + r - 3;
    int iw = ccol - 3;
    float v = 0.f;
    if ((unsigned)id < (unsigned)IN && (unsigned)ih < (unsigned)IN &&
        (unsigned)iw < (unsigned)IN)
      v = (inc[(id * IN + ih) * IN + iw] - mean) * inv;
    patch[idx] = v;
  }
  for (int idx = tid; idx < 16 * 125; idx += 256) {
    int cs = idx / 125;
    int k  = idx - cs * 125;
    int co = co0 + cs;
    wsh[idx] = (co < 52) ? w[(size_t)co * 125 + k] : 0.f;
  }
  __syncthreads();

  #pragma unroll 1
  for (int kd = 0; kd < 5; ++kd) {
    #pragma unroll
    for (int kh = 0; kh < 5; ++kh) {
      #pragma unroll
      for (int kw = 0; kw < 5; ++kw) {
        const int k = (kd * 5 + kh) * 5 + kw;
        const float wa = wsh[co_sub * 125 + k];
        const float wb = wsh[(co_sub + 8) * 125 + k];
        #pragma unroll
        for (int p = 0; p < P; ++p) {
          float pv = patch[(kd * RR + rowb[p] + kh) * R + colb[p] + kw];
          acc0[p] += pv * wa;
          acc1[p] += pv * wb;
        }
      }
    }
  }

  const int co_a = co0 + co_sub;
  const int co_b = co_a + 8;
  const int no = n_out0 + blockIdx.z;
  #pragma unroll
  for (int p = 0; p < P; ++p) {
    int s = sb + 32 * p;
    if (s < SP) {
      int ohs = s / OUT;
      int ow  = s - ohs * OUT;
      int oh  = oh_base + ohs;
      if (oh < OUT) {
        size_t base = ((((size_t)no * OUT + od) * OUT + oh) * OUT + ow) * 52;
        if (co_a < 52) out[base + co_a] = f2bf(acc0[p]);
        if (co_b < 52) out[base + co_b] = f2bf(acc1[p]);
      }
    }
  }
}

// ---------------- MFMA implicit-GEMM conv, k=5 s=2 p=3 ----------------
// M = MT*16 output channels, N = OHG*OUT spatial (pad NT*16), K = 64cin x 125tap
// yin channels-last [n][IN^3][CINP]; wt [125][MT*16][64]; yout [n][OUT^3][MT*16]
__device__ inline int swz(int lin, int cs) {
  int row = lin >> 1;
  int slot = (((lin & 1) << 2) | cs) ^ (row & 7);
  return row * 128 + slot * 16;
}

template<int IN, int OUT, int OHG, int MT, int CINP>
__global__ __launch_bounds__(256) void conv_mfma(
    const short* __restrict__ yin, const short* __restrict__ wt,
    const float* __restrict__ affa, const float* __restrict__ affc,
    short* __restrict__ yout, int n_in0, int n_out0)
{
  constexpr int W = 2 * OUT + 3;
  constexpr int H = 2 * OHG + 3;
  constexpr int LIN = H * W;
  constexpr int ROWS = (LIN + 1) / 2;
  constexpr int NT = (OHG * OUT + 15) / 16;
  constexpr int CO = MT * 16;

  __shared__ __align__(16) char slab[ROWS * 128];
  __shared__ float s_a[64], s_c[64];

  const int tid = threadIdx.x;
  const int wv = tid >> 6, ln = tid & 63;
  const int oh0 = blockIdx.x * OHG;
  const int od  = blockIdx.y;
  const int nimg = blockIdx.z;

  if (tid < 64) { s_a[tid] = affa[tid]; s_c[tid] = affc[tid]; }

  // B-side / store-side per-lane precompute (n-col = ln&15)
  int linb[NT]; bool vld[NT]; long obase[NT];
  #pragma unroll
  for (int nt = 0; nt < NT; ++nt) {
    int n = nt * 16 + (ln & 15);
    int ohl = n / OUT, ow = n - ohl * OUT;
    bool v = (n < OHG * OUT) && (oh0 + ohl < OUT);
    vld[nt] = v;
    int lb = (2 * ohl) * W + 2 * ow;
    if (lb > LIN - 1 - 4 * W - 4) lb = LIN - 1 - 4 * W - 4;
    linb[nt] = lb;
    obase[nt] = (((((long)(n_out0 + nimg)) * OUT + od) * OUT + (oh0 + ohl)) * OUT + ow) * CO;
  }

  const int mt = (MT == 4) ? wv : 0;
  const int co_row = mt * 16 + (ln & 15);   // A-frag row
  const int cs = ln >> 4;                   // k-subgroup (8 cin)
  const bool act = (MT == 4) || (wv < NT);

  f32x4 acc[NT];
  #pragma unroll
  for (int nt = 0; nt < NT; ++nt) acc[nt] = (f32x4){0.f, 0.f, 0.f, 0.f};

  const int id_base = 2 * od - 3;
  const int ih_base = 2 * oh0 - 3;

  for (int ch = 0; ch < 2; ++ch) {
    for (int kd = 0; kd < 5; ++kd) {
      __syncthreads();
      // ---- stage slab: relu(a*y + c) for one (cin-chunk, kd) plane ----
      {
        const int id = id_base + kd;
        const bool dok = (unsigned)id < (unsigned)IN;
        for (int u = tid; u < LIN * 4; u += 256) {
          int lin = u >> 2, cs2 = u & 3;
          int hl = lin / W, wl = lin - hl * W;
          int ih = ih_base + hl;
          int iw = wl - 3;
          float f[8];
          #pragma unroll
          for (int e = 0; e < 8; ++e) f[e] = 0.f;
          if (dok && (unsigned)ih < (unsigned)IN && (unsigned)iw < (unsigned)IN) {
            size_t base = ((((size_t)nimg * IN + id) * IN + ih) * IN + iw) * CINP
                          + ch * 32 + cs2 * 8;
            if constexpr (CINP == 64) {
              bf16x8 ld = *(const bf16x8*)(yin + base);
              #pragma unroll
              for (int e = 0; e < 8; ++e) {
                int c = ch * 32 + cs2 * 8 + e;
                f[e] = fmaxf(s_a[c] * bf2f(ld[e]) + s_c[c], 0.f);
              }
            } else {
              short4v lo = *(const short4v*)(yin + base);
              short4v hi = *(const short4v*)(yin + base + 4);
              #pragma unroll
              for (int e = 0; e < 4; ++e) {
                int c = ch * 32 + cs2 * 8 + e;
                f[e] = fmaxf(s_a[c] * bf2f(lo[e]) + s_c[c], 0.f);
              }
              #pragma unroll
              for (int e = 0; e < 4; ++e) {
                int c = ch * 32 + cs2 * 8 + 4 + e;
                f[4 + e] = fmaxf(s_a[c] * bf2f(hi[e]) + s_c[c], 0.f);
              }
            }
          }
          bf16x8 pk;
          #pragma unroll
          for (int e = 0; e < 8; ++e) pk[e] = f2bf(f[e]);
          *(bf16x8*)(slab + swz(lin, cs2)) = pk;
        }
      }
      __syncthreads();
      // ---- compute: 5 kh x 5 kw taps on this kd plane ----
      if (act) {
        for (int kh = 0; kh < 5; ++kh) {
          const int tapb = (kd * 5 + kh) * 5;
          bf16x8 afr[5];
          #pragma unroll
          for (int kw = 0; kw < 5; ++kw)
            afr[kw] = *(const bf16x8*)(wt + ((size_t)(tapb + kw) * CO + co_row) * 64
                                       + ch * 32 + cs * 8);
          #pragma unroll
          for (int nt = 0; nt < NT; ++nt) {
            if (MT == 1 && nt != wv) continue;
            const int lin0 = linb[nt] + kh * W;
            const int ai = (MT == 1) ? 0 : nt;
            #pragma unroll
            for (int kw = 0; kw < 5; ++kw) {
              bf16x8 b = *(const bf16x8*)(slab + swz(lin0 + kw, cs));
              acc[ai] = __builtin_amdgcn_mfma_f32_16x16x32_bf16(
                  afr[kw], b, acc[ai], 0, 0, 0);
            }
          }
        }
      }
    }
  }

  // ---- store: D[m][n], m = mt*16 + (ln>>4)*4 + r, n = ln&15 ----
  #pragma unroll
  for (int nt = 0; nt < NT; ++nt) {
    if (MT == 1 && nt != wv) continue;
    if (!act || !vld[nt]) continue;
    const int ai = (MT == 1) ? 0 : nt;
    short4v pk;
    #pragma unroll
    for (int r = 0; r < 4; ++r) pk[r] = f2bf(acc[ai][r]);
    *(short4v*)(yout + obase[nt] + mt * 16 + (ln >> 4) * 4) = pk;
  }
}

// ---------------- global avg pool + affine batch-dim BN (y3 CL-16) ----------
__global__ __launch_bounds__(320) void pool_bn(
    const short* __restrict__ y3, const float* __restrict__ gamma,
    const float* __restrict__ beta, float* __restrict__ out)
{
  __shared__ float pool[320];
  const int t = threadIdx.x;
  const int n = t / 10, c = t % 10;
  const short* p = y3 + (size_t)n * 216 * 16 + c;
  float s = 0.f;
  for (int i = 0; i < 216; ++i) s += bf2f(p[i * 16]);
  const float pv = s * (1.0f / 216.0f);
  pool[t] = pv;
  __syncthreads();
  float m = 0.f, m2 = 0.f;
  for (int nn = 0; nn < 32; ++nn) {
    float v = pool[nn * 10 + c];
    m += v; m2 += v * v;
  }
  m *= (1.0f / 32.0f);
  m2 = m2 * (1.0f / 32.0f) - m * m;
  out[t] = (pv - m) * rsqrtf(m2 + EPSV) * gamma[c] + beta[c];
}

// ---------------- launcher ----------------
extern "C" void kernel_launch(void* const* d_in, const int* in_sizes, int n_in,
                              void* d_out, int out_size, void* d_ws, size_t ws_size,
                              hipStream_t stream)
{
  const float* x  = (const float*)d_in[0];
  const float* w0 = (const float*)d_in[1];
  const float* b0 = (const float*)d_in[2];
  const float* w1 = (const float*)d_in[3];
  const float* b1 = (const float*)d_in[4];
  const float* w2 = (const float*)d_in[5];
  const float* b2 = (const float*)d_in[6];
  const float* w3 = (const float*)d_in[7];
  const float* gamma = (const float*)d_in[8];
  const float* beta  = (const float*)d_in[9];
  float* out = (float*)d_out;

  char* base = (char*)d_ws;
  size_t off = 0;
  auto alloc = [&](size_t bytes) -> void* {
    void* p = base + off;
    off = (off + bytes + 255) & ~(size_t)255;
    return p;
  };
  short* y1  = (short*)alloc((size_t)32 * 5832 * 64 * 2);   // 23.9 MB
  short* y2  = (short*)alloc((size_t)32 * 1000 * 64 * 2);   //  4.1 MB
  short* y3  = (short*)alloc((size_t)32 * 216 * 16 * 2);    //  0.22 MB
  short* w1t = (short*)alloc((size_t)125 * 64 * 64 * 2);    //  1.0 MB
  short* w2t = (short*)alloc((size_t)125 * 64 * 64 * 2);
  short* w3t = (short*)alloc((size_t)125 * 16 * 64 * 2);
  float* st_in = (float*)alloc(1024);
  float* st0 = (float*)alloc(1024);
  float* st1 = (float*)alloc(1024);
  float* st2 = (float*)alloc(1024);
  float* a0 = (float*)alloc(256); float* c0 = (float*)alloc(256);
  float* a1 = (float*)alloc(256); float* c1 = (float*)alloc(256);
  float* a2 = (float*)alloc(256); float* c2 = (float*)alloc(256);
  float* part = (float*)alloc(131072);
  short* y0 = (short*)(base + off);                          // remaining
  size_t rem = (ws_size > off + 256) ? (ws_size - off - 256) : 0; // 256B slack
  const size_t Y0_IMG = (size_t)35937 * 52;                  // elems/image
  int CH;
  if      (rem >= Y0_IMG * 32 * 2) CH = 32;
  else if (rem >= Y0_IMG * 16 * 2) CH = 16;
  else if (rem >= Y0_IMG * 8 * 2)  CH = 8;
  else if (rem >= Y0_IMG * 4 * 2)  CH = 4;
  else if (rem >= Y0_IMG * 2 * 2)  CH = 2;
  else                             CH = 1;

  // weight repacks (deterministic, every call)
  repack_k<<<512, 256, 0, stream>>>(w1, w1t, 52, 52, 64);
  repack_k<<<512, 256, 0, stream>>>(w2, w2t, 52, 52, 64);
  repack_k<<<256, 256, 0, stream>>>(w3, w3t, 10, 52, 16);

  // x stats
  reduce_partial_f32<<<128, 256, 0, stream>>>(x, 64 * 64 * 64, part, 128, 0);
  reduce_final<<<1, 64, 0, stream>>>(part, 128, 1, st_in);

  const float cnt0 = 1.0f / ((float)NB * 35937.0f);
  const float cnt1 = 1.0f / ((float)NB * 5832.0f);
  const float cnt2 = 1.0f / ((float)NB * 1000.0f);

  if (CH == 32) {
    conv0_k<<<dim3(4, 165, 32), 256, 0, stream>>>(x, w0, st_in, y0, 0, 0);
    reduce_cl<<<128, 256, 0, stream>>>(y0, 52, (long)32 * 35937, part, 128, 0);
    reduce_final<<<64, 64, 0, stream>>>(part, 128, 64, st0);
    aff_k<<<1, 64, 0, stream>>>(st0, b0, cnt0, 52, a0, c0);
    conv_mfma<33, 18, 2, 4, 52><<<dim3(9, 18, 32), 256, 0, stream>>>(
        y0, w1t, a0, c0, y1, 0, 0);
  } else {
    const int nch = 32 / CH;
    for (int ck = 0; ck < nch; ++ck) {
      conv0_k<<<dim3(4, 165, CH), 256, 0, stream>>>(x, w0, st_in, y0, ck * CH, 0);
      reduce_cl<<<4, 256, 0, stream>>>(y0, 52, (long)CH * 35937, part, nch * 4, ck * 4);
    }
    reduce_final<<<64, 64, 0, stream>>>(part, nch * 4, 64, st0);
    aff_k<<<1, 64, 0, stream>>>(st0, b0, cnt0, 52, a0, c0);
    for (int ck = 0; ck < nch; ++ck) {
      conv0_k<<<dim3(4, 165, CH), 256, 0, stream>>>(x, w0, st_in, y0, ck * CH, 0);
      conv_mfma<33, 18, 2, 4, 52><<<dim3(9, 18, CH), 256, 0, stream>>>(
          y0, w1t, a0, c0, y1, 0, ck * CH);
    }
  }

  reduce_cl<<<64, 256, 0, stream>>>(y1, 64, (long)32 * 5832, part, 64, 0);
  reduce_final<<<64, 64, 0, stream>>>(part, 64, 64, st1);
  aff_k<<<1, 64, 0, stream>>>(st1, b1, cnt1, 52, a1, c1);

  conv_mfma<18, 10, 4, 4, 64><<<dim3(3, 10, 32), 256, 0, stream>>>(
      y1, w2t, a1, c1, y2, 0, 0);

  reduce_cl<<<16, 256, 0, stream>>>(y2, 64, (long)32 * 1000, part, 16, 0);
  reduce_final<<<64, 64, 0, stream>>>(part, 16, 64, st2);
  aff_k<<<1, 64, 0, stream>>>(st2, b2, cnt2, 52, a2, c2);

  conv_mfma<10, 6, 6, 1, 64><<<dim3(1, 6, 32), 256, 0, stream>>>(
      y2, w3t, a2, c2, y3, 0, 0);

  pool_bn<<<1, 320, 0, stream>>>(y3, gamma, beta, out);
}

// Round 6
// 2001.572 us; speedup vs baseline: 3.3145x; 1.3409x over previous
//
#include <hip/hip_runtime.h>
#include <hip/hip_bf16.h>

#define EPSV 1e-5f
constexpr int NB = 32;

typedef short bf16x8 __attribute__((ext_vector_type(8)));
typedef short short4v __attribute__((ext_vector_type(4)));
typedef float f32x4 __attribute__((ext_vector_type(4)));

__device__ inline float bf2f(short s) {
  return __uint_as_float(((unsigned)(unsigned short)s) << 16);
}
__device__ inline short f2bf(float f) {
  unsigned u = __float_as_uint(f);
  unsigned r = (u + 0x7FFFu + ((u >> 16) & 1u)) >> 16;
  return (short)r;
}

// ---------------- x stats (NCDHW, C=1) ----------------
__global__ __launch_bounds__(256) void reduce_partial_f32(
    const float* __restrict__ in, int spatial, float* __restrict__ part,
    int totb, int boff)
{
  const int b = blockIdx.x;
  const int nblk = gridDim.x;
  float s = 0.f, s2 = 0.f;
  for (int n = 0; n < NB; ++n) {
    const float* p = in + (size_t)n * spatial;
    for (int i = b * 256 + threadIdx.x; i < spatial; i += nblk * 256) {
      float v = p[i];
      s += v; s2 += v * v;
    }
  }
  __shared__ float sh[256], sh2[256];
  int tid = threadIdx.x;
  sh[tid] = s; sh2[tid] = s2;
  __syncthreads();
  for (int off = 128; off > 0; off >>= 1) {
    if (tid < off) { sh[tid] += sh[tid + off]; sh2[tid] += sh2[tid + off]; }
    __syncthreads();
  }
  if (tid == 0) {
    part[(size_t)(boff + b) * 2 + 0] = sh[0];
    part[(size_t)(boff + b) * 2 + 1] = sh2[0];
  }
}

// ---------------- channels-last per-channel stats ----------------
__global__ __launch_bounds__(256) void reduce_cl(
    const short* __restrict__ y, int rowlen, long nrows,
    float* __restrict__ part, int totb, int boff)
{
  const int b = blockIdx.x, nblk = gridDim.x;
  const int c = threadIdx.x & 63, seg = threadIdx.x >> 6;
  float s = 0.f, s2 = 0.f;
  if (c < rowlen) {
    for (long r = (long)b * 4 + seg; r < nrows; r += (long)nblk * 4) {
      float v = bf2f(y[r * rowlen + c]);
      s += v; s2 += v * v;
    }
  }
  __shared__ float sh[4][64], sh2[4][64];
  sh[seg][c] = s; sh2[seg][c] = s2;
  __syncthreads();
  if (seg == 0) {
    float a = sh[0][c] + sh[1][c] + sh[2][c] + sh[3][c];
    float a2 = sh2[0][c] + sh2[1][c] + sh2[2][c] + sh2[3][c];
    part[((size_t)c * totb + boff + b) * 2 + 0] = a;
    part[((size_t)c * totb + boff + b) * 2 + 1] = a2;
  }
}

__global__ __launch_bounds__(64) void reduce_final(
    const float* __restrict__ part, int nblk, int C, float* __restrict__ sums)
{
  const int c = blockIdx.x;
  float s = 0.f, s2 = 0.f;
  for (int b = threadIdx.x; b < nblk; b += 64) {
    s  += part[((size_t)c * nblk + b) * 2 + 0];
    s2 += part[((size_t)c * nblk + b) * 2 + 1];
  }
  for (int off = 32; off > 0; off >>= 1) {
    s  += __shfl_down(s, off);
    s2 += __shfl_down(s2, off);
  }
  if (threadIdx.x == 0) { sums[c] = s; sums[C + c] = s2; }
}

// ---------------- stats -> per-channel affine (a*x + c, for relu(BN(x)+b)) ----
__global__ __launch_bounds__(64) void aff_k(
    const float* __restrict__ st, const float* __restrict__ bias,
    float cnt_inv, int creal, float* __restrict__ a, float* __restrict__ c)
{
  int t = threadIdx.x;
  float mean = st[t] * cnt_inv;
  float var  = st[64 + t] * cnt_inv - mean * mean;
  float inv  = rsqrtf(var + EPSV);
  bool ok = t < creal;
  a[t] = ok ? inv : 0.f;
  c[t] = ok ? (-mean * inv + bias[t]) : 0.f;
}

// ---------------- weight repack: w[CO][CIN][125] fp32 -> wt[125][COP][64] bf16
__global__ __launch_bounds__(256) void repack_k(
    const float* __restrict__ w, short* __restrict__ wt,
    int CO, int CIN, int COP)
{
  long total = 125L * COP * 64;
  for (long idx = (long)blockIdx.x * 256 + threadIdx.x; idx < total;
       idx += (long)gridDim.x * 256) {
    int tap = (int)(idx / (COP * 64));
    int r   = (int)(idx % (COP * 64));
    int co = r >> 6, ci = r & 63;
    float v = (co < CO && ci < CIN) ? w[((size_t)co * CIN + ci) * 125 + tap] : 0.f;
    wt[idx] = f2bf(v);
  }
}

// ---------------- w0 repack: w0[52][125] fp32 -> w0t[64 co][128 k] bf16 -------
__global__ __launch_bounds__(256) void repack_w0(
    const float* __restrict__ w, short* __restrict__ wt)
{
  for (int idx = blockIdx.x * 256 + threadIdx.x; idx < 64 * 128;
       idx += gridDim.x * 256) {
    int co = idx >> 7, k = idx & 127;
    float v = (co < 52 && k < 125) ? w[co * 125 + k] : 0.f;
    wt[idx] = f2bf(v);
  }
}

// ---------------- conv0 MFMA: CIN=1, K=125 taps, BN(x) on stage -------------
// M = 64 co (4 m-tiles, 1/wave), K = 128, N-tile = 64 spatial of an od-plane.
// x fp32 [img][64^3]; w0t [64][128] bf16; out channels-last [img][33^3][52].
__global__ __launch_bounds__(256) void conv0_mfma(
    const float* __restrict__ x, const short* __restrict__ w0t,
    const float* __restrict__ stats, short* __restrict__ out,
    int n_in0, int n_out0)
{
  constexpr int IN = 64, OUT = 33;
  constexpr float CNTI = 1.0f / ((float)NB * IN * IN * IN);
  __shared__ __align__(16) char slab[64 * 256];   // [n 64][k-slot 16][16B], swz

  const int tid = threadIdx.x;
  const int wv = tid >> 6, ln = tid & 63;
  const int cs = ln >> 4;
  const int ntile0 = blockIdx.x * 64;
  const int od = blockIdx.y;
  const int img = blockIdx.z;

  const float mean = stats[0] * CNTI;
  const float inv  = rsqrtf(stats[1] * CNTI - mean * mean + EPSV);

  // A fragments: co = wv*16 + (ln&15), k = ks*32 + cs*8 (held in regs)
  bf16x8 afr[4];
  {
    const short* wrow = w0t + (wv * 16 + (ln & 15)) * 128 + cs * 8;
    #pragma unroll
    for (int ks = 0; ks < 4; ++ks) afr[ks] = *(const bf16x8*)(wrow + ks * 32);
  }

  // ---- stage im2col slab: 64 n x 128 k, BN applied, bf16 ----
  const float* xi = x + (size_t)(n_in0 + img) * (IN * IN * IN);
  const int id_base = 2 * od - 3;
  for (int u = tid; u < 1024; u += 256) {
    const int nl = u >> 4, s = u & 15;
    const int ng = ntile0 + nl;
    const int oh = ng / OUT, ow = ng - oh * OUT;
    const bool nok = ng < OUT * OUT;
    const int ih_base = 2 * oh - 3, iw_base = 2 * ow - 3;
    bf16x8 pk;
    #pragma unroll
    for (int e = 0; e < 8; ++e) {
      const int k = s * 8 + e;
      float f = 0.f;
      if (nok && k < 125) {
        const int kd = k / 25, r = k - kd * 25;
        const int kh = r / 5, kw = r - kh * 5;
        const int id = id_base + kd, ih = ih_base + kh, iw = iw_base + kw;
        if ((unsigned)id < (unsigned)IN && (unsigned)ih < (unsigned)IN &&
            (unsigned)iw < (unsigned)IN)
          f = (xi[((size_t)id * IN + ih) * IN + iw] - mean) * inv;
      }
      pk[e] = f2bf(f);
    }
    const int slot = (s & 8) | ((s & 7) ^ (nl & 7));
    *(bf16x8*)(slab + nl * 256 + slot * 16) = pk;
  }
  __syncthreads();

  // ---- compute + store: wave wv owns co-tile wv*16..+15 ----
  const int nl = ln & 15;
  #pragma unroll
  for (int nt = 0; nt < 4; ++nt) {
    f32x4 acc = (f32x4){0.f, 0.f, 0.f, 0.f};
    const int nn = nt * 16 + nl;
    #pragma unroll
    for (int ks = 0; ks < 4; ++ks) {
      const int s = ks * 4 + cs;
      const int slot = (s & 8) | ((s & 7) ^ (nn & 7));
      bf16x8 b = *(const bf16x8*)(slab + nn * 256 + slot * 16);
      acc = __builtin_amdgcn_mfma_f32_16x16x32_bf16(afr[ks], b, acc, 0, 0, 0);
    }
    const int ng = ntile0 + nn;
    const int co = wv * 16 + cs * 4;
    if (ng < OUT * OUT && co < 52) {
      const int oh = ng / OUT, ow = ng - oh * OUT;
      short4v pk;
      #pragma unroll
      for (int r = 0; r < 4; ++r) pk[r] = f2bf(acc[r]);
      size_t base = ((((size_t)(n_out0 + img) * OUT + od) * OUT + oh) * OUT + ow) * 52;
      *(short4v*)(out + base + co) = pk;
    }
  }
}

// ---------------- MFMA implicit-GEMM conv, k=5 s=2 p=3 ----------------
__device__ inline int swz(int lin, int cs) {
  int row = lin >> 1;
  int slot = (((lin & 1) << 2) | cs) ^ (row & 7);
  return row * 128 + slot * 16;
}

template<int IN, int OUT, int OHG, int MT, int CINP>
__global__ __launch_bounds__(256) void conv_mfma(
    const short* __restrict__ yin, const short* __restrict__ wt,
    const float* __restrict__ affa, const float* __restrict__ affc,
    short* __restrict__ yout, int n_in0, int n_out0)
{
  constexpr int W = 2 * OUT + 3;
  constexpr int H = 2 * OHG + 3;
  constexpr int LIN = H * W;
  constexpr int ROWS = (LIN + 1) / 2;
  constexpr int NT = (OHG * OUT + 15) / 16;
  constexpr int CO = MT * 16;

  __shared__ __align__(16) char slab[ROWS * 128];
  __shared__ float s_a[64], s_c[64];

  const int tid = threadIdx.x;
  const int wv = tid >> 6, ln = tid & 63;
  const int oh0 = blockIdx.x * OHG;
  const int od  = blockIdx.y;
  const int nimg = blockIdx.z;

  if (tid < 64) { s_a[tid] = affa[tid]; s_c[tid] = affc[tid]; }

  int linb[NT]; bool vld[NT]; long obase[NT];
  #pragma unroll
  for (int nt = 0; nt < NT; ++nt) {
    int n = nt * 16 + (ln & 15);
    int ohl = n / OUT, ow = n - ohl * OUT;
    bool v = (n < OHG * OUT) && (oh0 + ohl < OUT);
    vld[nt] = v;
    int lb = (2 * ohl) * W + 2 * ow;
    if (lb > LIN - 1 - 4 * W - 4) lb = LIN - 1 - 4 * W - 4;
    linb[nt] = lb;
    obase[nt] = (((((long)(n_out0 + nimg)) * OUT + od) * OUT + (oh0 + ohl)) * OUT + ow) * CO;
  }

  const int mt = (MT == 4) ? wv : 0;
  const int co_row = mt * 16 + (ln & 15);
  const int cs = ln >> 4;
  const bool act = (MT == 4) || (wv < NT);

  f32x4 acc[NT];
  #pragma unroll
  for (int nt = 0; nt < NT; ++nt) acc[nt] = (f32x4){0.f, 0.f, 0.f, 0.f};

  const int id_base = 2 * od - 3;
  const int ih_base = 2 * oh0 - 3;

  for (int ch = 0; ch < 2; ++ch) {
    for (int kd = 0; kd < 5; ++kd) {
      __syncthreads();
      {
        const int id = id_base + kd;
        const bool dok = (unsigned)id < (unsigned)IN;
        for (int u = tid; u < LIN * 4; u += 256) {
          int lin = u >> 2, cs2 = u & 3;
          int hl = lin / W, wl = lin - hl * W;
          int ih = ih_base + hl;
          int iw = wl - 3;
          float f[8];
          #pragma unroll
          for (int e = 0; e < 8; ++e) f[e] = 0.f;
          if (dok && (unsigned)ih < (unsigned)IN && (unsigned)iw < (unsigned)IN) {
            size_t base = ((((size_t)nimg * IN + id) * IN + ih) * IN + iw) * CINP
                          + ch * 32 + cs2 * 8;
            if constexpr (CINP == 64) {
              bf16x8 ld = *(const bf16x8*)(yin + base);
              #pragma unroll
              for (int e = 0; e < 8; ++e) {
                int c = ch * 32 + cs2 * 8 + e;
                f[e] = fmaxf(s_a[c] * bf2f(ld[e]) + s_c[c], 0.f);
              }
            } else {
              short4v lo = *(const short4v*)(yin + base);
              short4v hi = *(const short4v*)(yin + base + 4);
              #pragma unroll
              for (int e = 0; e < 4; ++e) {
                int c = ch * 32 + cs2 * 8 + e;
                f[e] = fmaxf(s_a[c] * bf2f(lo[e]) + s_c[c], 0.f);
              }
              #pragma unroll
              for (int e = 0; e < 4; ++e) {
                int c = ch * 32 + cs2 * 8 + 4 + e;
                f[4 + e] = fmaxf(s_a[c] * bf2f(hi[e]) + s_c[c], 0.f);
              }
            }
          }
          bf16x8 pk;
          #pragma unroll
          for (int e = 0; e < 8; ++e) pk[e] = f2bf(f[e]);
          *(bf16x8*)(slab + swz(lin, cs2)) = pk;
        }
      }
      __syncthreads();
      if (act) {
        for (int kh = 0; kh < 5; ++kh) {
          const int tapb = (kd * 5 + kh) * 5;
          bf16x8 afr[5];
          #pragma unroll
          for (int kw = 0; kw < 5; ++kw)
            afr[kw] = *(const bf16x8*)(wt + ((size_t)(tapb + kw) * CO + co_row) * 64
                                       + ch * 32 + cs * 8);
          #pragma unroll
          for (int nt = 0; nt < NT; ++nt) {
            if (MT == 1 && nt != wv) continue;
            const int lin0 = linb[nt] + kh * W;
            const int ai = (MT == 1) ? 0 : nt;
            #pragma unroll
            for (int kw = 0; kw < 5; ++kw) {
              bf16x8 b = *(const bf16x8*)(slab + swz(lin0 + kw, cs));
              acc[ai] = __builtin_amdgcn_mfma_f32_16x16x32_bf16(
                  afr[kw], b, acc[ai], 0, 0, 0);
            }
          }
        }
      }
    }
  }

  #pragma unroll
  for (int nt = 0; nt < NT; ++nt) {
    if (MT == 1 && nt != wv) continue;
    if (!act || !vld[nt]) continue;
    const int ai = (MT == 1) ? 0 : nt;
    short4v pk;
    #pragma unroll
    for (int r = 0; r < 4; ++r) pk[r] = f2bf(acc[ai][r]);
    *(short4v*)(yout + obase[nt] + mt * 16 + (ln >> 4) * 4) = pk;
  }
}

// ---------------- global avg pool + affine batch-dim BN (y3 CL-16) ----------
__global__ __launch_bounds__(320) void pool_bn(
    const short* __restrict__ y3, const float* __restrict__ gamma,
    const float* __restrict__ beta, float* __restrict__ out)
{
  __shared__ float pool[320];
  const int t = threadIdx.x;
  const int n = t / 10, c = t % 10;
  const short* p = y3 + (size_t)n * 216 * 16 + c;
  float s = 0.f;
  for (int i = 0; i < 216; ++i) s += bf2f(p[i * 16]);
  const float pv = s * (1.0f / 216.0f);
  pool[t] = pv;
  __syncthreads();
  float m = 0.f, m2 = 0.f;
  for (int nn = 0; nn < 32; ++nn) {
    float v = pool[nn * 10 + c];
    m += v; m2 += v * v;
  }
  m *= (1.0f / 32.0f);
  m2 = m2 * (1.0f / 32.0f) - m * m;
  out[t] = (pv - m) * rsqrtf(m2 + EPSV) * gamma[c] + beta[c];
}

// ---------------- launcher ----------------
extern "C" void kernel_launch(void* const* d_in, const int* in_sizes, int n_in,
                              void* d_out, int out_size, void* d_ws, size_t ws_size,
                              hipStream_t stream)
{
  const float* x  = (const float*)d_in[0];
  const float* w0 = (const float*)d_in[1];
  const float* b0 = (const float*)d_in[2];
  const float* w1 = (const float*)d_in[3];
  const float* b1 = (const float*)d_in[4];
  const float* w2 = (const float*)d_in[5];
  const float* b2 = (const float*)d_in[6];
  const float* w3 = (const float*)d_in[7];
  const float* gamma = (const float*)d_in[8];
  const float* beta  = (const float*)d_in[9];
  float* out = (float*)d_out;

  char* base = (char*)d_ws;
  size_t off = 0;
  auto alloc = [&](size_t bytes) -> void* {
    void* p = base + off;
    off = (off + bytes + 255) & ~(size_t)255;
    return p;
  };
  short* y1  = (short*)alloc((size_t)32 * 5832 * 64 * 2);   // 23.9 MB
  short* y2  = (short*)alloc((size_t)32 * 1000 * 64 * 2);   //  4.1 MB
  short* y3  = (short*)alloc((size_t)32 * 216 * 16 * 2);    //  0.22 MB
  short* w1t = (short*)alloc((size_t)125 * 64 * 64 * 2);    //  1.0 MB
  short* w2t = (short*)alloc((size_t)125 * 64 * 64 * 2);
  short* w3t = (short*)alloc((size_t)125 * 16 * 64 * 2);
  short* w0t = (short*)alloc((size_t)64 * 128 * 2);         // 16 KB
  float* st_in = (float*)alloc(1024);
  float* st0 = (float*)alloc(1024);
  float* st1 = (float*)alloc(1024);
  float* st2 = (float*)alloc(1024);
  float* a0 = (float*)alloc(256); float* c0 = (float*)alloc(256);
  float* a1 = (float*)alloc(256); float* c1 = (float*)alloc(256);
  float* a2 = (float*)alloc(256); float* c2 = (float*)alloc(256);
  float* part = (float*)alloc(131072);
  short* y0 = (short*)(base + off);                          // remaining
  size_t rem = (ws_size > off + 256) ? (ws_size - off - 256) : 0;
  const size_t Y0_IMG = (size_t)35937 * 52;
  int CH;
  if      (rem >= Y0_IMG * 32 * 2) CH = 32;
  else if (rem >= Y0_IMG * 16 * 2) CH = 16;
  else if (rem >= Y0_IMG * 8 * 2)  CH = 8;
  else if (rem >= Y0_IMG * 4 * 2)  CH = 4;
  else if (rem >= Y0_IMG * 2 * 2)  CH = 2;
  else                             CH = 1;

  // weight repacks (deterministic, every call)
  repack_k<<<512, 256, 0, stream>>>(w1, w1t, 52, 52, 64);
  repack_k<<<512, 256, 0, stream>>>(w2, w2t, 52, 52, 64);
  repack_k<<<256, 256, 0, stream>>>(w3, w3t, 10, 52, 16);
  repack_w0<<<32, 256, 0, stream>>>(w0, w0t);

  // x stats
  reduce_partial_f32<<<128, 256, 0, stream>>>(x, 64 * 64 * 64, part, 128, 0);
  reduce_final<<<1, 64, 0, stream>>>(part, 128, 1, st_in);

  const float cnt0 = 1.0f / ((float)NB * 35937.0f);
  const float cnt1 = 1.0f / ((float)NB * 5832.0f);
  const float cnt2 = 1.0f / ((float)NB * 1000.0f);

  if (CH == 32) {
    conv0_mfma<<<dim3(18, 33, 32), 256, 0, stream>>>(x, w0t, st_in, y0, 0, 0);
    reduce_cl<<<128, 256, 0, stream>>>(y0, 52, (long)32 * 35937, part, 128, 0);
    reduce_final<<<64, 64, 0, stream>>>(part, 128, 64, st0);
    aff_k<<<1, 64, 0, stream>>>(st0, b0, cnt0, 52, a0, c0);
    conv_mfma<33, 18, 2, 4, 52><<<dim3(9, 18, 32), 256, 0, stream>>>(
        y0, w1t, a0, c0, y1, 0, 0);
  } else {
    const int nch = 32 / CH;
    for (int ck = 0; ck < nch; ++ck) {
      conv0_mfma<<<dim3(18, 33, CH), 256, 0, stream>>>(x, w0t, st_in, y0, ck * CH, 0);
      reduce_cl<<<4, 256, 0, stream>>>(y0, 52, (long)CH * 35937, part, nch * 4, ck * 4);
    }
    reduce_final<<<64, 64, 0, stream>>>(part, nch * 4, 64, st0);
    aff_k<<<1, 64, 0, stream>>>(st0, b0, cnt0, 52, a0, c0);
    for (int ck = 0; ck < nch; ++ck) {
      conv0_mfma<<<dim3(18, 33, CH), 256, 0, stream>>>(x, w0t, st_in, y0, ck * CH, 0);
      conv_mfma<33, 18, 2, 4, 52><<<dim3(9, 18, CH), 256, 0, stream>>>(
          y0, w1t, a0, c0, y1, 0, ck * CH);
    }
  }

  reduce_cl<<<64, 256, 0, stream>>>(y1, 64, (long)32 * 5832, part, 64, 0);
  reduce_final<<<64, 64, 0, stream>>>(part, 64, 64, st1);
  aff_k<<<1, 64, 0, stream>>>(st1, b1, cnt1, 52, a1, c1);

  conv_mfma<18, 10, 4, 4, 64><<<dim3(3, 10, 32), 256, 0, stream>>>(
      y1, w2t, a1, c1, y2, 0, 0);

  reduce_cl<<<16, 256, 0, stream>>>(y2, 64, (long)32 * 1000, part, 16, 0);
  reduce_final<<<64, 64, 0, stream>>>(part, 16, 64, st2);
  aff_k<<<1, 64, 0, stream>>>(st2, b2, cnt2, 52, a2, c2);

  conv_mfma<10, 6, 6, 1, 64><<<dim3(1, 6, 32), 256, 0, stream>>>(
      y2, w3t, a2, c2, y3, 0, 0);

  pool_bn<<<1, 320, 0, stream>>>(y3, gamma, beta, out);
}